// Round 6
// baseline (40.557 us; speedup 1.0000x reference)
//
#include <hip/hip_runtime.h>

typedef _Float16 half4 __attribute__((ext_vector_type(4)));
typedef _Float16 h2 __attribute__((ext_vector_type(2)));
typedef float f32x4 __attribute__((ext_vector_type(4)));

#define SINCONST 0.07957747154594767f  // 0.5 rad in revolutions

__device__ __forceinline__ unsigned int pk(float a, float b) {
    return __builtin_bit_cast(unsigned int, __builtin_amdgcn_cvt_pkrtz(a, b));
}

// state factors for one patch: a = (c0c1,c0s1,s0c1,s0s1) dup-packed, q = (c2c3,c2s3,s2c3,s2s3)
__device__ __forceinline__ void factors(float px0, float px1, float px2, float px3,
                                        uint4& ad, uint2& qd) {
    float t0 = px0 * SINCONST, t1 = px1 * SINCONST;
    float t2 = px2 * SINCONST, t3 = px3 * SINCONST;
    float s0 = __builtin_amdgcn_sinf(t0), c0 = __builtin_amdgcn_cosf(t0);
    float s1 = __builtin_amdgcn_sinf(t1), c1 = __builtin_amdgcn_cosf(t1);
    float s2 = __builtin_amdgcn_sinf(t2), c2 = __builtin_amdgcn_cosf(t2);
    float s3 = __builtin_amdgcn_sinf(t3), c3 = __builtin_amdgcn_cosf(t3);
    float a0 = c0 * c1, a1 = c0 * s1, a2 = s0 * c1, a3 = s0 * s1;
    float q0 = c2 * c3, q1 = c2 * s3, q2 = s2 * c3, q3 = s2 * s3;
    ad.x = pk(a0, a0); ad.y = pk(a1, a1); ad.z = pk(a2, a2); ad.w = pk(a3, a3);
    qd.x = pk(q0, q1); qd.y = pk(q2, q3);
}

// Per wave macro-iter: 128 patches (64 aligned pairs, one float4 top + one float4 bottom per lane).
// LDS per wave-buffer (768 dwords): adup[128][4] u32 @ [0,512), qv[128] u32x2 @ [512,768).
// Phase2: 8 MFMA sub-batches of 16 patches; fragment conventions identical to validated kernel.
__global__ __launch_bounds__(256) void quanv(
    const float* __restrict__ x,
    const float* __restrict__ U,
    float* __restrict__ out,
    int total, int ipw, int rem)
{
    __shared__ __align__(16) unsigned int smem[4 * 2 * 768];  // 24 KiB

    const int tid  = threadIdx.x;
    const int lane = tid & 63;
    const int wib  = tid >> 6;
    const int wave = (blockIdx.x * 256 + tid) >> 6;
    const int p16  = lane & 15;
    const int g    = lane >> 4;

    unsigned int* wsmem = smem + wib * (2 * 768);

    // A1 = U fragment: U[p16][4g+i]  (validated layout)
    half4 aU;
    {
        const float* up = U + p16 * 16 + 4 * g;
        aU[0] = (_Float16)up[0];
        aU[1] = (_Float16)up[1];
        aU[2] = (_Float16)up[2];
        aU[3] = (_Float16)up[3];
    }
    // A2 = tiled PauliZ signs: Ztile[p16][e=4g+i], wire=p16&3 (exact in f16)
    half4 aS;
    {
        int w = p16 & 3;
        #pragma unroll
        for (int i = 0; i < 4; ++i) {
            int e = 4 * g + i;
            aS[i] = ((e >> (3 - w)) & 1) ? (_Float16)-1.f : (_Float16)1.f;
        }
    }

    int cnt = ipw + (wave < rem ? 1 : 0);
    if (cnt <= 0) return;
    const int mac0 = wave * ipw + (wave < rem ? wave : rem);
    const int nPairs = total >> 1;

    // load pixels for this lane's patch pair of macro-iter j
    auto ldp = [&](int j, float4& t4, float4& b4) {
        int PR = (mac0 + j) * 64 + lane;
        if (PR >= nPairs) PR = nPairs - 1;
        int P   = PR * 2;
        int img = P / 196;                  // compiler magic-mul
        int pp  = P - img * 196;            // even, [0,194]
        int r   = (pp * 2341) >> 15;        // pp/14
        const float4* ptr = reinterpret_cast<const float4*>(x + img * 784 + 2 * pp + 28 * r);
        t4 = ptr[0];                        // top row: patches P,P+1
        b4 = ptr[7];                        // +28 floats
    };

    float4 cT, cB, nT, nB;
    ldp(0, cT, cB);
    nT = cT; nB = cB;
    if (cnt > 1) ldp(1, nT, nB);

    for (int j = 0; j < cnt; ++j) {
        // prefetch j+2 (depth-2 pipeline)
        float4 fT = nT, fB = nB;
        if (j + 2 < cnt) ldp(j + 2, fT, fB);

        // ---- phase 1: two patches -> f16 factors -> LDS ----
        uint4 adA, adB; uint2 qdA, qdB;
        factors(cT.x, cT.y, cB.x, cB.y, adA, qdA);   // patch P   (even)
        factors(cT.z, cT.w, cB.z, cB.w, adB, qdB);   // patch P+1

        unsigned int* buf = wsmem + (j & 1) * 768;
        *reinterpret_cast<uint4*>(buf + 8 * lane)     = adA;   // adup rows 2l, 2l+1
        *reinterpret_cast<uint4*>(buf + 8 * lane + 4) = adB;
        uint4 qq = make_uint4(qdA.x, qdA.y, qdB.x, qdB.y);     // qv rows 2l, 2l+1
        *reinterpret_cast<uint4*>(buf + 512 + 4 * lane) = qq;

        // ---- phase 2: 8 MFMA sub-batches ----
        const int pbase = (mac0 + j) * 128;
        #pragma unroll
        for (int t = 0; t < 8; ++t) {
            const int pt = t * 16 + p16;
            unsigned int adw = buf[pt * 4 + g];                              // imm 256*t
            uint2 qw = *reinterpret_cast<const uint2*>(buf + 512 + 2 * pt);  // imm 2048+128*t

            h2 ag  = __builtin_bit_cast(h2, adw);
            h2 q01 = __builtin_bit_cast(h2, qw.x);
            h2 q23 = __builtin_bit_cast(h2, qw.y);
            h2 blo = ag * q01;                     // v_pk_mul_f16
            h2 bhi = ag * q23;
            half4 bST = __builtin_shufflevector(blo, bhi, 0, 1, 2, 3);

            const f32x4 zero4 = {0.f, 0.f, 0.f, 0.f};
            f32x4 y = __builtin_amdgcn_mfma_f32_16x16x16f16(aU, bST, zero4, 0, 0, 0);

            h2 y01 = __builtin_bit_cast(h2, pk(y[0], y[1]));
            h2 y23 = __builtin_bit_cast(h2, pk(y[2], y[3]));
            h2 p01 = y01 * y01;
            h2 p23 = y23 * y23;
            half4 bP = __builtin_shufflevector(p01, p23, 0, 1, 2, 3);

            f32x4 m = __builtin_amdgcn_mfma_f32_16x16x16f16(aS, bP, zero4, 0, 0, 0);

            int Ps = pbase + pt;
            if (g == 0 && Ps < total) {
                float4 res = make_float4(m[0], m[1], m[2], m[3]);
                *reinterpret_cast<float4*>(out + (size_t)Ps * 4) = res;
            }
        }

        cT = nT; cB = nB;
        nT = fT; nB = fB;
    }
}

extern "C" void kernel_launch(void* const* d_in, const int* in_sizes, int n_in,
                              void* d_out, int out_size, void* d_ws, size_t ws_size,
                              hipStream_t stream) {
    const float* x = (const float*)d_in[0];
    const float* U = (const float*)d_in[1];
    float* out = (float*)d_out;

    int B = in_sizes[0] / 784;
    int total = B * 196;                  // 6,422,528 patches
    int nPairs = total / 2;               // 3,211,264 aligned pairs
    int nmac = (nPairs + 63) / 64;        // 50,176 macro-iters (128 patches each)

    int nblocks = 2048;
    int nwaves = nblocks * (256 / 64);    // 8192 waves -> 6-7 macro-iters/wave
    int ipw = nmac / nwaves;
    int rem = nmac % nwaves;

    quanv<<<nblocks, 256, 0, stream>>>(x, U, out, total, ipw, rem);
}